// Round 1
// baseline (978.370 us; speedup 1.0000x reference)
//
#include <hip/hip_runtime.h>
#include <hip/hip_fp16.h>
#include <math.h>

#define NN 2048
#define PP 4096
#define DD 128
#define SS 150
#define THR 204

// ws layout (float offsets)
#define OFF_POOLN 0
#define OFF_POOLT 524288
#define OFF_WTH   1048576   // 16384 halves = 8192 floats
#define OFF_NEG   1056768
#define OFF_REFL  1060864
#define OFF_POSD  1064960
#define OFF_TOPI  1069056   // 4096*204 ints

// ---------------- prep: normalize pool rows, write normal + transposed ----------------
__global__ void prep_norm(const float* __restrict__ z1, const float* __restrict__ z2,
                          float* __restrict__ pool_n, float* __restrict__ pool_nT) {
    int b = blockIdx.x;          // pool row 0..4095
    int l = threadIdx.x;         // 0..63
    const float* src = (b < NN) ? z1 + (size_t)b * DD : z2 + (size_t)(b - NN) * DD;
    float2 v = *(const float2*)(src + 2 * l);
    float ss = v.x * v.x + v.y * v.y;
    #pragma unroll
    for (int mask = 1; mask < 64; mask <<= 1) ss += __shfl_xor(ss, mask);
    float inv = 1.0f / fmaxf(sqrtf(ss), 1e-12f);
    float2 nv; nv.x = v.x * inv; nv.y = v.y * inv;
    *(float2*)(pool_n + (size_t)b * DD + 2 * l) = nv;
    pool_nT[(size_t)(2 * l) * PP + b]     = nv.x;
    pool_nT[(size_t)(2 * l + 1) * PP + b] = nv.y;
}

// ---------------- prep: transpose proj_w -> fp16, layout [k][d] ----------------
__global__ void prep_wt(const float* __restrict__ pw, __half* __restrict__ wt_h) {
    int e = blockIdx.x * 256 + threadIdx.x;   // 0..16383
    int k = e >> 7, d = e & 127;
    wt_h[e] = __float2half(pw[d * DD + k]);
}

__device__ __forceinline__ int swz(int j) {
    return ((j & 63) << 6) | ((j >> 6) ^ (j & 31));
}

// ---------------- Gram rows + expsum + top-204 ----------------
__global__ __launch_bounds__(256, 2) void simtopk(
    const float* __restrict__ pool_n, const float* __restrict__ pool_nT,
    float* __restrict__ negsum, float* __restrict__ refl, float* __restrict__ posd,
    int* __restrict__ topidx) {
    __shared__ float sims[4 * PP];   // 64 KB, XOR-swizzled per row
    int tid = threadIdx.x;
    int r0 = blockIdx.x * 4;

    float acc[4][16];
    #pragma unroll
    for (int r = 0; r < 4; r++)
        #pragma unroll
        for (int e = 0; e < 16; e++) acc[r][e] = 0.f;

    const float4* pt4 = (const float4*)pool_nT;
    for (int k = 0; k < DD; k++) {
        float4 p0 = pt4[k * 1024 + tid];
        float4 p1 = pt4[k * 1024 + 256 + tid];
        float4 p2 = pt4[k * 1024 + 512 + tid];
        float4 p3 = pt4[k * 1024 + 768 + tid];
        #pragma unroll
        for (int r = 0; r < 4; r++) {
            float qk = pool_n[(size_t)(r0 + r) * DD + k];   // uniform -> scalar load
            acc[r][0]  += qk * p0.x; acc[r][1]  += qk * p0.y; acc[r][2]  += qk * p0.z; acc[r][3]  += qk * p0.w;
            acc[r][4]  += qk * p1.x; acc[r][5]  += qk * p1.y; acc[r][6]  += qk * p1.z; acc[r][7]  += qk * p1.w;
            acc[r][8]  += qk * p2.x; acc[r][9]  += qk * p2.y; acc[r][10] += qk * p2.z; acc[r][11] += qk * p2.w;
            acc[r][12] += qk * p3.x; acc[r][13] += qk * p3.y; acc[r][14] += qk * p3.z; acc[r][15] += qk * p3.w;
        }
    }

    // exp-sum per row (covers the whole row incl. diagonals, matching k=2N top_k sum)
    #pragma unroll
    for (int r = 0; r < 4; r++) {
        float es = 0.f;
        #pragma unroll
        for (int e = 0; e < 16; e++) es += expf(2.0f * acc[r][e]);
        #pragma unroll
        for (int mask = 1; mask < 64; mask <<= 1) es += __shfl_xor(es, mask);
        if ((tid & 63) == 0) atomicAdd(&negsum[r0 + r], es);
    }

    // stash sims in swizzled LDS
    #pragma unroll
    for (int r = 0; r < 4; r++)
        #pragma unroll
        for (int jj = 0; jj < 4; jj++)
            #pragma unroll
            for (int c = 0; c < 4; c++) {
                int j = jj * 1024 + tid * 4 + c;
                sims[r * PP + swz(j)] = acc[r][jj * 4 + c];
            }
    __syncthreads();

    // per-wave: one row each
    int w = tid >> 6, l = tid & 63;
    float* srow = sims + w * PP;
    int rg = r0 + w;
    if (l == 0) {
        refl[rg] = srow[swz(rg)];
        posd[rg] = srow[swz(rg ^ NN)];
    }
    // cached per-lane argmax over owned entries {j : j%64 == l}
    float lv = -INFINITY; int lj = 0;
    for (int c = 0; c < 64; c++) {
        float v = srow[(l << 6) | (c ^ (l & 31))];
        if (v > lv) { lv = v; lj = c * 64 + l; }
    }
    for (int t = 0; t < THR; t++) {
        float bv = lv; int bj = lj;
        #pragma unroll
        for (int mask = 1; mask < 64; mask <<= 1) {
            float ov = __shfl_xor(bv, mask);
            int   oj = __shfl_xor(bj, mask);
            if (ov > bv || (ov == bv && oj < bj)) { bv = ov; bj = oj; }
        }
        if (l == 0) topidx[(size_t)rg * THR + t] = bj;
        int wl = bj & 63;                 // owner lane of the winner
        if (l == wl) srow[(wl << 6) | ((bj >> 6) ^ (wl & 31))] = -INFINITY;
        asm volatile("s_waitcnt lgkmcnt(0)" ::: "memory");
        // cooperative rescan of owner's 64 slots
        float rv = srow[(wl << 6) | (l ^ (wl & 31))];
        int   rj = l * 64 + wl;
        #pragma unroll
        for (int mask = 1; mask < 64; mask <<= 1) {
            float ov = __shfl_xor(rv, mask);
            int   oj = __shfl_xor(rj, mask);
            if (ov > rv || (ov == rv && oj < rj)) { rv = ov; rj = oj; }
        }
        if (l == wl) { lv = rv; lj = rj; }
    }
}

// ---------------- mix + project + normalize + dot + loss ----------------
__global__ __launch_bounds__(256, 3) void mixloss(
    const float* __restrict__ z1, const float* __restrict__ z2,
    const float* __restrict__ proj_b, const float* __restrict__ pool_n,
    const __half* __restrict__ wt_h,
    const float* __restrict__ negsum, const float* __restrict__ refl,
    const float* __restrict__ posd, const int* __restrict__ topidx,
    const int* __restrict__ idx1, const int* __restrict__ idx2,
    float* __restrict__ out) {
    __shared__ __half wt_s[DD * DD];      // 32 KB, [k][d]
    __shared__ float q_sh[DD], b_sh[DD];
    __shared__ int top_sh[THR];
    __shared__ int idx_sh[2 * SS];
    __shared__ float m_sh[4][8][DD];      // 16 KB
    __shared__ float red2[4];

    int tid = threadIdx.x;
    int r = blockIdx.x;                   // 0..4095 ; side = r>>11, i = r&2047
    int i = r & (NN - 1);
    const int* idxp = ((r >= NN) ? idx2 : idx1) + (size_t)i * (2 * SS);

    const unsigned* wtg = (const unsigned*)wt_h;
    unsigned* wts = (unsigned*)wt_s;
    for (int e = tid; e < 8192; e += 256) wts[e] = wtg[e];
    if (tid < DD) { q_sh[tid] = pool_n[(size_t)r * DD + tid]; b_sh[tid] = proj_b[tid]; }
    if (tid < THR) top_sh[tid] = topidx[(size_t)r * THR + tid];
    for (int e = tid; e < 2 * SS; e += 256) idx_sh[e] = idxp[e];
    __syncthreads();

    int w = tid >> 6, l = tid & 63;
    float wavesum = 0.f;

    for (int g = 0; g < 5; g++) {
        #pragma unroll
        for (int u = 0; u < 8; u++) {
            int t = g * 32 + w * 8 + u;
            if (t < SS) {
                int c1 = top_sh[idx_sh[t]];
                int c2 = top_sh[idx_sh[t + SS]];
                const float* pa = (c1 < NN) ? z1 + (size_t)c1 * DD : z2 + (size_t)(c1 - NN) * DD;
                const float* pb = (c2 < NN) ? z1 + (size_t)c2 * DD : z2 + (size_t)(c2 - NN) * DD;
                float2 a = *(const float2*)(pa + 2 * l);
                float2 b = *(const float2*)(pb + 2 * l);
                float2 m; m.x = 0.2f * a.x + 0.8f * b.x; m.y = 0.2f * a.y + 0.8f * b.y;
                *(float2*)&m_sh[w][u][2 * l] = m;
            }
        }
        __syncthreads();

        float acc[8][2];
        #pragma unroll
        for (int u = 0; u < 8; u++) { acc[u][0] = b_sh[2 * l]; acc[u][1] = b_sh[2 * l + 1]; }
        for (int k = 0; k < DD; k++) {
            __half2 wh = ((const __half2*)wt_s)[k * 64 + l];   // (k,2l),(k,2l+1)
            float2 wf = __half22float2(wh);
            #pragma unroll
            for (int u = 0; u < 8; u++) {
                float mk = m_sh[w][u][k];
                acc[u][0] += mk * wf.x;
                acc[u][1] += mk * wf.y;
            }
        }
        float q0 = q_sh[2 * l], q1 = q_sh[2 * l + 1];
        #pragma unroll
        for (int u = 0; u < 8; u++) {
            int t = g * 32 + w * 8 + u;
            if (t < SS) {
                float n2 = acc[u][0] * acc[u][0] + acc[u][1] * acc[u][1];
                float dt = acc[u][0] * q0 + acc[u][1] * q1;
                #pragma unroll
                for (int mask = 1; mask < 64; mask <<= 1) {
                    n2 += __shfl_xor(n2, mask);
                    dt += __shfl_xor(dt, mask);
                }
                wavesum += expf(2.0f * dt / fmaxf(sqrtf(n2), 1e-12f));
            }
        }
        __syncthreads();
    }

    if (l == 0) red2[w] = wavesum;
    __syncthreads();
    if (tid == 0) {
        float negm = red2[0] + red2[1] + red2[2] + red2[3];
        float den = negsum[r] + negm - refl[r];
        float loss = logf(den) - 2.0f * posd[r];
        atomicAdd(out, loss * (1.0f / 4096.0f));
    }
}

extern "C" void kernel_launch(void* const* d_in, const int* in_sizes, int n_in,
                              void* d_out, int out_size, void* d_ws, size_t ws_size,
                              hipStream_t stream) {
    const float* z1  = (const float*)d_in[0];
    const float* z2  = (const float*)d_in[1];
    const float* pw  = (const float*)d_in[2];
    const float* pb  = (const float*)d_in[3];
    const int* idx1  = (const int*)d_in[4];
    const int* idx2  = (const int*)d_in[5];
    float* out = (float*)d_out;

    float* wsf = (float*)d_ws;
    float* pool_n  = wsf + OFF_POOLN;
    float* pool_nT = wsf + OFF_POOLT;
    __half* wt_h   = (__half*)(wsf + OFF_WTH);
    float* negs    = wsf + OFF_NEG;
    float* rfl     = wsf + OFF_REFL;
    float* psd     = wsf + OFF_POSD;
    int*   topi    = (int*)(wsf + OFF_TOPI);

    hipMemsetAsync(d_out, 0, sizeof(float), stream);
    hipMemsetAsync(negs, 0, PP * sizeof(float), stream);

    prep_norm<<<PP, 64, 0, stream>>>(z1, z2, pool_n, pool_nT);
    prep_wt<<<64, 256, 0, stream>>>(pw, wt_h);
    simtopk<<<PP / 4, 256, 0, stream>>>(pool_n, pool_nT, negs, rfl, psd, topi);
    mixloss<<<PP, 256, 0, stream>>>(z1, z2, pb, pool_n, wt_h, negs, rfl, psd, topi,
                                    idx1, idx2, out);
}

// Round 2
// 709.603 us; speedup vs baseline: 1.3788x; 1.3788x over previous
//
#include <hip/hip_runtime.h>
#include <hip/hip_fp16.h>
#include <math.h>

#define NN 2048
#define PP 4096
#define DD 128
#define SS 150
#define THR 204
#define ROWS 8
#define CAP 512

// ws layout (float offsets)
#define OFF_POOLN 0
#define OFF_POOLT 524288
#define OFF_WTH   1048576   // 16384 halves = 8192 floats
#define OFF_NEG   1056768
#define OFF_REFL  1060864
#define OFF_POSD  1064960
#define OFF_TOPI  1069056   // 4096*204 ints

// ---------------- prep: normalize pool rows, write normal + transposed ----------------
__global__ void prep_norm(const float* __restrict__ z1, const float* __restrict__ z2,
                          float* __restrict__ pool_n, float* __restrict__ pool_nT) {
    int b = blockIdx.x;          // pool row 0..4095
    int l = threadIdx.x;         // 0..63
    const float* src = (b < NN) ? z1 + (size_t)b * DD : z2 + (size_t)(b - NN) * DD;
    float2 v = *(const float2*)(src + 2 * l);
    float ss = v.x * v.x + v.y * v.y;
    #pragma unroll
    for (int mask = 1; mask < 64; mask <<= 1) ss += __shfl_xor(ss, mask);
    float inv = 1.0f / fmaxf(sqrtf(ss), 1e-12f);
    float2 nv; nv.x = v.x * inv; nv.y = v.y * inv;
    *(float2*)(pool_n + (size_t)b * DD + 2 * l) = nv;
    pool_nT[(size_t)(2 * l) * PP + b]     = nv.x;
    pool_nT[(size_t)(2 * l + 1) * PP + b] = nv.y;
}

// ---------------- prep: transpose proj_w -> fp16, layout [k][d] ----------------
__global__ void prep_wt(const float* __restrict__ pw, __half* __restrict__ wt_h) {
    int e = blockIdx.x * 256 + threadIdx.x;   // 0..16383
    int k = e >> 7, d = e & 127;
    wt_h[e] = __float2half(pw[d * DD + k]);
}

// order-preserving float->uint key (larger float => larger key)
__device__ __forceinline__ unsigned fkey(float v) {
    unsigned u = __float_as_uint(v);
    return u ^ (unsigned)(((int)u >> 31) | 0x80000000);
}

// ---------------- Gram rows + expsum + top-204 via radix-select + rank ----------------
__global__ __launch_bounds__(256, 2) void simtopk(
    const float* __restrict__ pool_n, const float* __restrict__ pool_nT,
    float* __restrict__ negsum, float* __restrict__ refl, float* __restrict__ posd,
    int* __restrict__ topidx) {
    __shared__ float q_sh[ROWS][DD];          // 4 KB
    __shared__ int hist[ROWS][256];           // 8 KB
    __shared__ uint2 cand[ROWS][CAP];         // 32 KB  {key, col}
    __shared__ int rowB[ROWS], rowCum[ROWS], rowP[ROWS], cnt[ROWS];
    __shared__ float partial[ROWS][4];

    int tid = threadIdx.x, w = tid >> 6, l = tid & 63;
    int r0 = blockIdx.x * ROWS;

    for (int e = tid; e < ROWS * DD; e += 256)
        q_sh[e >> 7][e & 127] = pool_n[(size_t)r0 * DD + e];
    __syncthreads();

    float acc[ROWS][16];
    #pragma unroll
    for (int r = 0; r < ROWS; r++)
        #pragma unroll
        for (int e = 0; e < 16; e++) acc[r][e] = 0.f;

    // gram: thread tid owns cols {jj*1024 + tid*4 + c}
    const float4* pt4 = (const float4*)pool_nT;
    for (int k = 0; k < DD; k++) {
        float4 p0 = pt4[k * 1024 + tid];
        float4 p1 = pt4[k * 1024 + 256 + tid];
        float4 p2 = pt4[k * 1024 + 512 + tid];
        float4 p3 = pt4[k * 1024 + 768 + tid];
        #pragma unroll
        for (int r = 0; r < ROWS; r++) {
            float qk = q_sh[r][k];
            acc[r][0]  += qk * p0.x; acc[r][1]  += qk * p0.y; acc[r][2]  += qk * p0.z; acc[r][3]  += qk * p0.w;
            acc[r][4]  += qk * p1.x; acc[r][5]  += qk * p1.y; acc[r][6]  += qk * p1.z; acc[r][7]  += qk * p1.w;
            acc[r][8]  += qk * p2.x; acc[r][9]  += qk * p2.y; acc[r][10] += qk * p2.z; acc[r][11] += qk * p2.w;
            acc[r][12] += qk * p3.x; acc[r][13] += qk * p3.y; acc[r][14] += qk * p3.z; acc[r][15] += qk * p3.w;
        }
    }

    // expsum (full row, matches k=2N top_k sum) + refl/posd (all acc indices constant)
    #pragma unroll
    for (int r = 0; r < ROWS; r++) {
        int rg = r0 + r;
        float es = 0.f;
        #pragma unroll
        for (int e = 0; e < 16; e++) {
            es += expf(2.0f * acc[r][e]);
            int col = (e >> 2) * 1024 + (tid << 2) + (e & 3);
            if (col == rg) refl[rg] = acc[r][e];
            if (col == (rg ^ NN)) posd[rg] = acc[r][e];
        }
        #pragma unroll
        for (int mask = 1; mask < 64; mask <<= 1) es += __shfl_xor(es, mask);
        if (l == 0) partial[r][w] = es;
    }

    // ---- radix pass 1: 256-bin hist of key[31:24] ----
    for (int e = tid; e < ROWS * 256; e += 256) ((int*)hist)[e] = 0;
    if (tid < ROWS) cnt[tid] = 0;
    __syncthreads();
    if (tid < ROWS) negsum[r0 + tid] = partial[tid][0] + partial[tid][1] + partial[tid][2] + partial[tid][3];
    #pragma unroll
    for (int r = 0; r < ROWS; r++)
        #pragma unroll
        for (int e = 0; e < 16; e++)
            atomicAdd(&hist[r][fkey(acc[r][e]) >> 24], 1);
    __syncthreads();

    // scan1: wave w handles rows w, w+4
    for (int rr = w; rr < ROWS; rr += 4) {
        int4 h4 = ((const int4*)hist[rr])[l];     // bins 4l..4l+3
        int s = h4.x + h4.y + h4.z + h4.w;
        int suf = s;
        #pragma unroll
        for (int off = 1; off < 64; off <<= 1) {
            int x = __shfl_down(suf, off);
            if (l + off < 64) suf += x;
        }
        int A = suf - s;                           // count above this lane's bins
        int ca3 = A, ca2 = A + h4.w, ca1 = ca2 + h4.z, ca0 = ca1 + h4.y;
        if (ca3 < THR && THR <= ca3 + h4.w) { rowB[rr] = 4 * l + 3; rowCum[rr] = ca3; }
        if (ca2 < THR && THR <= ca2 + h4.z) { rowB[rr] = 4 * l + 2; rowCum[rr] = ca2; }
        if (ca1 < THR && THR <= ca1 + h4.y) { rowB[rr] = 4 * l + 1; rowCum[rr] = ca1; }
        if (ca0 < THR && THR <= ca0 + h4.x) { rowB[rr] = 4 * l + 0; rowCum[rr] = ca0; }
    }
    __syncthreads();

    // ---- radix pass 2: hist of key[23:16] within selected top-8 bin ----
    for (int e = tid; e < ROWS * 256; e += 256) ((int*)hist)[e] = 0;
    __syncthreads();
    #pragma unroll
    for (int r = 0; r < ROWS; r++) {
        int B = rowB[r];
        #pragma unroll
        for (int e = 0; e < 16; e++) {
            unsigned key = fkey(acc[r][e]);
            if ((int)(key >> 24) == B) atomicAdd(&hist[r][(key >> 16) & 255], 1);
        }
    }
    __syncthreads();

    for (int rr = w; rr < ROWS; rr += 4) {
        int base = rowCum[rr];
        int4 h4 = ((const int4*)hist[rr])[l];
        int s = h4.x + h4.y + h4.z + h4.w;
        int suf = s;
        #pragma unroll
        for (int off = 1; off < 64; off <<= 1) {
            int x = __shfl_down(suf, off);
            if (l + off < 64) suf += x;
        }
        int A = base + suf - s;
        int ca3 = A, ca2 = A + h4.w, ca1 = ca2 + h4.z, ca0 = ca1 + h4.y;
        if (ca3 < THR && THR <= ca3 + h4.w) rowP[rr] = (rowB[rr] << 8) | (4 * l + 3);
        if (ca2 < THR && THR <= ca2 + h4.z) rowP[rr] = (rowB[rr] << 8) | (4 * l + 2);
        if (ca1 < THR && THR <= ca1 + h4.y) rowP[rr] = (rowB[rr] << 8) | (4 * l + 1);
        if (ca0 < THR && THR <= ca0 + h4.x) rowP[rr] = (rowB[rr] << 8) | (4 * l + 0);
    }
    __syncthreads();

    // ---- collect candidates with key>>16 >= P16 ----
    #pragma unroll
    for (int r = 0; r < ROWS; r++) {
        unsigned P16 = (unsigned)rowP[r];
        #pragma unroll
        for (int e = 0; e < 16; e++) {
            unsigned key = fkey(acc[r][e]);
            if ((key >> 16) >= P16) {
                int p = atomicAdd(&cnt[r], 1);
                if (p < CAP) {
                    int col = (e >> 2) * 1024 + (tid << 2) + (e & 3);
                    cand[r][p] = make_uint2(key, (unsigned)col);
                }
            }
        }
    }
    __syncthreads();

    // ---- rank candidates (key desc, col asc) ----
    for (int rr = w; rr < ROWS; rr += 4) {
        int C = min(cnt[rr], CAP);
        int rg = r0 + rr;
        unsigned km[8]; int im[8], rk[8];
        #pragma unroll
        for (int o = 0; o < 8; o++) {
            int b = l + o * 64;
            bool v = (b < C);
            uint2 cd = v ? cand[rr][b] : make_uint2(0u, 0u);
            km[o] = cd.x; im[o] = (int)cd.y; rk[o] = v ? 0 : (THR + CAP);
        }
        for (int c = 0; c < C; c++) {
            uint2 cd = cand[rr][c];
            unsigned kc = cd.x; int ic = (int)cd.y;
            #pragma unroll
            for (int o = 0; o < 8; o++)
                if (o * 64 < C)
                    rk[o] += (kc > km[o] || (kc == km[o] && ic < im[o])) ? 1 : 0;
        }
        #pragma unroll
        for (int o = 0; o < 8; o++)
            if (rk[o] < THR) topidx[(size_t)rg * THR + rk[o]] = im[o];
    }
}

// ---------------- mix + project + normalize + dot + loss ----------------
__global__ __launch_bounds__(256, 3) void mixloss(
    const float* __restrict__ z1, const float* __restrict__ z2,
    const float* __restrict__ proj_b, const float* __restrict__ pool_n,
    const __half* __restrict__ wt_h,
    const float* __restrict__ negsum, const float* __restrict__ refl,
    const float* __restrict__ posd, const int* __restrict__ topidx,
    const int* __restrict__ idx1, const int* __restrict__ idx2,
    float* __restrict__ out) {
    __shared__ __half wt_s[DD * DD];      // 32 KB, [k][d]
    __shared__ float q_sh[DD], b_sh[DD];
    __shared__ int top_sh[THR];
    __shared__ int idx_sh[2 * SS];
    __shared__ float m_sh[4][8][DD];      // 16 KB
    __shared__ float red2[4];

    int tid = threadIdx.x;
    int r = blockIdx.x;                   // 0..4095 ; side = r>>11, i = r&2047
    int i = r & (NN - 1);
    const int* idxp = ((r >= NN) ? idx2 : idx1) + (size_t)i * (2 * SS);

    const unsigned* wtg = (const unsigned*)wt_h;
    unsigned* wts = (unsigned*)wt_s;
    for (int e = tid; e < 8192; e += 256) wts[e] = wtg[e];
    if (tid < DD) { q_sh[tid] = pool_n[(size_t)r * DD + tid]; b_sh[tid] = proj_b[tid]; }
    if (tid < THR) top_sh[tid] = topidx[(size_t)r * THR + tid];
    for (int e = tid; e < 2 * SS; e += 256) idx_sh[e] = idxp[e];
    __syncthreads();

    int w = tid >> 6, l = tid & 63;
    float wavesum = 0.f;

    for (int g = 0; g < 5; g++) {
        #pragma unroll
        for (int u = 0; u < 8; u++) {
            int t = g * 32 + w * 8 + u;
            if (t < SS) {
                int c1 = top_sh[idx_sh[t]];
                int c2 = top_sh[idx_sh[t + SS]];
                const float* pa = (c1 < NN) ? z1 + (size_t)c1 * DD : z2 + (size_t)(c1 - NN) * DD;
                const float* pb = (c2 < NN) ? z1 + (size_t)c2 * DD : z2 + (size_t)(c2 - NN) * DD;
                float2 a = *(const float2*)(pa + 2 * l);
                float2 b = *(const float2*)(pb + 2 * l);
                float2 m; m.x = 0.2f * a.x + 0.8f * b.x; m.y = 0.2f * a.y + 0.8f * b.y;
                *(float2*)&m_sh[w][u][2 * l] = m;
            }
        }
        __syncthreads();

        float acc[8][2];
        #pragma unroll
        for (int u = 0; u < 8; u++) { acc[u][0] = b_sh[2 * l]; acc[u][1] = b_sh[2 * l + 1]; }
        for (int k = 0; k < DD; k++) {
            __half2 wh = ((const __half2*)wt_s)[k * 64 + l];   // (k,2l),(k,2l+1)
            float2 wf = __half22float2(wh);
            #pragma unroll
            for (int u = 0; u < 8; u++) {
                float mk = m_sh[w][u][k];
                acc[u][0] += mk * wf.x;
                acc[u][1] += mk * wf.y;
            }
        }
        float q0 = q_sh[2 * l], q1 = q_sh[2 * l + 1];
        #pragma unroll
        for (int u = 0; u < 8; u++) {
            int t = g * 32 + w * 8 + u;
            if (t < SS) {
                float n2 = acc[u][0] * acc[u][0] + acc[u][1] * acc[u][1];
                float dt = acc[u][0] * q0 + acc[u][1] * q1;
                #pragma unroll
                for (int mask = 1; mask < 64; mask <<= 1) {
                    n2 += __shfl_xor(n2, mask);
                    dt += __shfl_xor(dt, mask);
                }
                wavesum += expf(2.0f * dt / fmaxf(sqrtf(n2), 1e-12f));
            }
        }
        __syncthreads();
    }

    if (l == 0) red2[w] = wavesum;
    __syncthreads();
    if (tid == 0) {
        float negm = red2[0] + red2[1] + red2[2] + red2[3];
        float den = negsum[r] + negm - refl[r];
        float loss = logf(den) - 2.0f * posd[r];
        atomicAdd(out, loss * (1.0f / 4096.0f));
    }
}

extern "C" void kernel_launch(void* const* d_in, const int* in_sizes, int n_in,
                              void* d_out, int out_size, void* d_ws, size_t ws_size,
                              hipStream_t stream) {
    const float* z1  = (const float*)d_in[0];
    const float* z2  = (const float*)d_in[1];
    const float* pw  = (const float*)d_in[2];
    const float* pb  = (const float*)d_in[3];
    const int* idx1  = (const int*)d_in[4];
    const int* idx2  = (const int*)d_in[5];
    float* out = (float*)d_out;

    float* wsf = (float*)d_ws;
    float* pool_n  = wsf + OFF_POOLN;
    float* pool_nT = wsf + OFF_POOLT;
    __half* wt_h   = (__half*)(wsf + OFF_WTH);
    float* negs    = wsf + OFF_NEG;
    float* rfl     = wsf + OFF_REFL;
    float* psd     = wsf + OFF_POSD;
    int*   topi    = (int*)(wsf + OFF_TOPI);

    hipMemsetAsync(d_out, 0, sizeof(float), stream);

    prep_norm<<<PP, 64, 0, stream>>>(z1, z2, pool_n, pool_nT);
    prep_wt<<<64, 256, 0, stream>>>(pw, wt_h);
    simtopk<<<PP / ROWS, 256, 0, stream>>>(pool_n, pool_nT, negs, rfl, psd, topi);
    mixloss<<<PP, 256, 0, stream>>>(z1, z2, pb, pool_n, wt_h, negs, rfl, psd, topi,
                                    idx1, idx2, out);
}

// Round 3
// 371.427 us; speedup vs baseline: 2.6341x; 1.9105x over previous
//
#include <hip/hip_runtime.h>
#include <math.h>

#define NN 2048
#define PP 4096
#define DD 128
#define SS 150
#define THR 204
#define ROWS 8
#define CAP 512

// ws layout (float offsets)
#define OFF_POOLN 0
#define OFF_POOLT 524288
#define OFF_WTT   1048576   // 16384 floats (W^T, [k][d])
#define OFF_PROJ  1064960   // 4096*128 floats = z_pool @ W^T
#define OFF_NEG   1589248
#define OFF_REFL  1593344
#define OFF_POSD  1597440
#define OFF_TOPI  1601536   // 4096*204 ints

// ---------------- prep: normalize pool rows, write normal + transposed ----------------
__global__ void prep_norm(const float* __restrict__ z1, const float* __restrict__ z2,
                          float* __restrict__ pool_n, float* __restrict__ pool_nT) {
    int b = blockIdx.x;          // pool row 0..4095
    int l = threadIdx.x;         // 0..63
    const float* src = (b < NN) ? z1 + (size_t)b * DD : z2 + (size_t)(b - NN) * DD;
    float2 v = *(const float2*)(src + 2 * l);
    float ss = v.x * v.x + v.y * v.y;
    #pragma unroll
    for (int mask = 1; mask < 64; mask <<= 1) ss += __shfl_xor(ss, mask);
    float inv = 1.0f / fmaxf(sqrtf(ss), 1e-12f);
    float2 nv; nv.x = v.x * inv; nv.y = v.y * inv;
    *(float2*)(pool_n + (size_t)b * DD + 2 * l) = nv;
    pool_nT[(size_t)(2 * l) * PP + b]     = nv.x;
    pool_nT[(size_t)(2 * l + 1) * PP + b] = nv.y;
}

// ---------------- prep: transpose proj_w (fp32), layout [k][d] ----------------
__global__ void prep_wt(const float* __restrict__ pw, float* __restrict__ wtT) {
    int e = blockIdx.x * 256 + threadIdx.x;   // 0..16383
    int k = e >> 7, d = e & 127;
    wtT[e] = pw[d * DD + k];
}

// ---------------- prep: P = z_pool @ W^T (no bias) ----------------
__global__ __launch_bounds__(256, 4) void prep_proj(
    const float* __restrict__ z1, const float* __restrict__ z2,
    const float* __restrict__ wtT, float* __restrict__ P) {
    __shared__ float z_sh[8][DD];
    int tid = threadIdx.x;
    int r0 = blockIdx.x * 8;
    for (int e = tid; e < 8 * DD; e += 256) {
        int rr = r0 + (e >> 7);
        z_sh[e >> 7][e & 127] = (rr < NN) ? z1[(size_t)rr * DD + (e & 127)]
                                          : z2[(size_t)(rr - NN) * DD + (e & 127)];
    }
    __syncthreads();
    int d = tid & 127, h = tid >> 7;
    float a0 = 0.f, a1 = 0.f, a2 = 0.f, a3 = 0.f;
    for (int k = 0; k < DD; k++) {
        float wv = wtT[k * DD + d];
        a0 += z_sh[4 * h + 0][k] * wv;
        a1 += z_sh[4 * h + 1][k] * wv;
        a2 += z_sh[4 * h + 2][k] * wv;
        a3 += z_sh[4 * h + 3][k] * wv;
    }
    P[(size_t)(r0 + 4 * h + 0) * DD + d] = a0;
    P[(size_t)(r0 + 4 * h + 1) * DD + d] = a1;
    P[(size_t)(r0 + 4 * h + 2) * DD + d] = a2;
    P[(size_t)(r0 + 4 * h + 3) * DD + d] = a3;
}

// order-preserving float->uint key (larger float => larger key)
__device__ __forceinline__ unsigned fkey(float v) {
    unsigned u = __float_as_uint(v);
    return u ^ (unsigned)(((int)u >> 31) | 0x80000000);
}

// ---------------- Gram rows + expsum + top-204 via radix-select + rank ----------------
__global__ __launch_bounds__(256, 2) void simtopk(
    const float* __restrict__ pool_n, const float* __restrict__ pool_nT,
    float* __restrict__ negsum, float* __restrict__ refl, float* __restrict__ posd,
    int* __restrict__ topidx) {
    __shared__ float q_sh[ROWS][DD];          // 4 KB
    __shared__ int hist[ROWS][256];           // 8 KB
    __shared__ uint2 cand[ROWS][CAP];         // 32 KB  {key, col}
    __shared__ int rowB[ROWS], rowCum[ROWS], rowP[ROWS], cnt[ROWS];
    __shared__ float partial[ROWS][4];

    int tid = threadIdx.x, w = tid >> 6, l = tid & 63;
    int r0 = blockIdx.x * ROWS;

    for (int e = tid; e < ROWS * DD; e += 256)
        q_sh[e >> 7][e & 127] = pool_n[(size_t)r0 * DD + e];
    __syncthreads();

    float acc[ROWS][16];
    #pragma unroll
    for (int r = 0; r < ROWS; r++)
        #pragma unroll
        for (int e = 0; e < 16; e++) acc[r][e] = 0.f;

    // gram: thread tid owns cols {jj*1024 + tid*4 + c}
    const float4* pt4 = (const float4*)pool_nT;
    for (int k = 0; k < DD; k++) {
        float4 p0 = pt4[k * 1024 + tid];
        float4 p1 = pt4[k * 1024 + 256 + tid];
        float4 p2 = pt4[k * 1024 + 512 + tid];
        float4 p3 = pt4[k * 1024 + 768 + tid];
        #pragma unroll
        for (int r = 0; r < ROWS; r++) {
            float qk = q_sh[r][k];
            acc[r][0]  += qk * p0.x; acc[r][1]  += qk * p0.y; acc[r][2]  += qk * p0.z; acc[r][3]  += qk * p0.w;
            acc[r][4]  += qk * p1.x; acc[r][5]  += qk * p1.y; acc[r][6]  += qk * p1.z; acc[r][7]  += qk * p1.w;
            acc[r][8]  += qk * p2.x; acc[r][9]  += qk * p2.y; acc[r][10] += qk * p2.z; acc[r][11] += qk * p2.w;
            acc[r][12] += qk * p3.x; acc[r][13] += qk * p3.y; acc[r][14] += qk * p3.z; acc[r][15] += qk * p3.w;
        }
    }

    // expsum (full row, matches k=2N top_k sum) + refl/posd (all acc indices constant)
    #pragma unroll
    for (int r = 0; r < ROWS; r++) {
        int rg = r0 + r;
        float es = 0.f;
        #pragma unroll
        for (int e = 0; e < 16; e++) {
            es += expf(2.0f * acc[r][e]);
            int col = (e >> 2) * 1024 + (tid << 2) + (e & 3);
            if (col == rg) refl[rg] = acc[r][e];
            if (col == (rg ^ NN)) posd[rg] = acc[r][e];
        }
        #pragma unroll
        for (int mask = 1; mask < 64; mask <<= 1) es += __shfl_xor(es, mask);
        if (l == 0) partial[r][w] = es;
    }

    // ---- radix pass 1: 256-bin hist of key[31:24] ----
    for (int e = tid; e < ROWS * 256; e += 256) ((int*)hist)[e] = 0;
    if (tid < ROWS) cnt[tid] = 0;
    __syncthreads();
    if (tid < ROWS) negsum[r0 + tid] = partial[tid][0] + partial[tid][1] + partial[tid][2] + partial[tid][3];
    #pragma unroll
    for (int r = 0; r < ROWS; r++)
        #pragma unroll
        for (int e = 0; e < 16; e++)
            atomicAdd(&hist[r][fkey(acc[r][e]) >> 24], 1);
    __syncthreads();

    // scan1: wave w handles rows w, w+4
    for (int rr = w; rr < ROWS; rr += 4) {
        int4 h4 = ((const int4*)hist[rr])[l];     // bins 4l..4l+3
        int s = h4.x + h4.y + h4.z + h4.w;
        int suf = s;
        #pragma unroll
        for (int off = 1; off < 64; off <<= 1) {
            int x = __shfl_down(suf, off);
            if (l + off < 64) suf += x;
        }
        int A = suf - s;                           // count above this lane's bins
        int ca3 = A, ca2 = A + h4.w, ca1 = ca2 + h4.z, ca0 = ca1 + h4.y;
        if (ca3 < THR && THR <= ca3 + h4.w) { rowB[rr] = 4 * l + 3; rowCum[rr] = ca3; }
        if (ca2 < THR && THR <= ca2 + h4.z) { rowB[rr] = 4 * l + 2; rowCum[rr] = ca2; }
        if (ca1 < THR && THR <= ca1 + h4.y) { rowB[rr] = 4 * l + 1; rowCum[rr] = ca1; }
        if (ca0 < THR && THR <= ca0 + h4.x) { rowB[rr] = 4 * l + 0; rowCum[rr] = ca0; }
    }
    __syncthreads();

    // ---- radix pass 2: hist of key[23:16] within selected top-8 bin ----
    for (int e = tid; e < ROWS * 256; e += 256) ((int*)hist)[e] = 0;
    __syncthreads();
    #pragma unroll
    for (int r = 0; r < ROWS; r++) {
        int B = rowB[r];
        #pragma unroll
        for (int e = 0; e < 16; e++) {
            unsigned key = fkey(acc[r][e]);
            if ((int)(key >> 24) == B) atomicAdd(&hist[r][(key >> 16) & 255], 1);
        }
    }
    __syncthreads();

    for (int rr = w; rr < ROWS; rr += 4) {
        int base = rowCum[rr];
        int4 h4 = ((const int4*)hist[rr])[l];
        int s = h4.x + h4.y + h4.z + h4.w;
        int suf = s;
        #pragma unroll
        for (int off = 1; off < 64; off <<= 1) {
            int x = __shfl_down(suf, off);
            if (l + off < 64) suf += x;
        }
        int A = base + suf - s;
        int ca3 = A, ca2 = A + h4.w, ca1 = ca2 + h4.z, ca0 = ca1 + h4.y;
        if (ca3 < THR && THR <= ca3 + h4.w) rowP[rr] = (rowB[rr] << 8) | (4 * l + 3);
        if (ca2 < THR && THR <= ca2 + h4.z) rowP[rr] = (rowB[rr] << 8) | (4 * l + 2);
        if (ca1 < THR && THR <= ca1 + h4.y) rowP[rr] = (rowB[rr] << 8) | (4 * l + 1);
        if (ca0 < THR && THR <= ca0 + h4.x) rowP[rr] = (rowB[rr] << 8) | (4 * l + 0);
    }
    __syncthreads();

    // ---- collect candidates with key>>16 >= P16 ----
    #pragma unroll
    for (int r = 0; r < ROWS; r++) {
        unsigned P16 = (unsigned)rowP[r];
        #pragma unroll
        for (int e = 0; e < 16; e++) {
            unsigned key = fkey(acc[r][e]);
            if ((key >> 16) >= P16) {
                int p = atomicAdd(&cnt[r], 1);
                if (p < CAP) {
                    int col = (e >> 2) * 1024 + (tid << 2) + (e & 3);
                    cand[r][p] = make_uint2(key, (unsigned)col);
                }
            }
        }
    }
    __syncthreads();

    // ---- rank candidates (key desc, col asc) ----
    for (int rr = w; rr < ROWS; rr += 4) {
        int C = min(cnt[rr], CAP);
        int rg = r0 + rr;
        unsigned km[8]; int im[8], rk[8];
        #pragma unroll
        for (int o = 0; o < 8; o++) {
            int b = l + o * 64;
            bool v = (b < C);
            uint2 cd = v ? cand[rr][b] : make_uint2(0u, 0u);
            km[o] = cd.x; im[o] = (int)cd.y; rk[o] = v ? 0 : (THR + CAP);
        }
        for (int c = 0; c < C; c++) {
            uint2 cd = cand[rr][c];
            unsigned kc = cd.x; int ic = (int)cd.y;
            #pragma unroll
            for (int o = 0; o < 8; o++)
                if (o * 64 < C)
                    rk[o] += (kc > km[o] || (kc == km[o] && ic < im[o])) ? 1 : 0;
        }
        #pragma unroll
        for (int o = 0; o < 8; o++)
            if (rk[o] < THR) topidx[(size_t)rg * THR + rk[o]] = im[o];
    }
}

// ---------------- mix (via linearity) + normalize + dot + loss ----------------
__global__ __launch_bounds__(256, 4) void mixloss(
    const float* __restrict__ P, const float* __restrict__ pool_n,
    const float* __restrict__ proj_b,
    const float* __restrict__ negsum, const float* __restrict__ refl,
    const float* __restrict__ posd, const int* __restrict__ topidx,
    const int* __restrict__ idx1, const int* __restrict__ idx2,
    float* __restrict__ out) {
    __shared__ int top_sh[THR];
    __shared__ int idx_sh[2 * SS];
    __shared__ float red2[4];

    int tid = threadIdx.x, w = tid >> 6, l = tid & 63;
    int r = blockIdx.x;                   // 0..4095
    int i = r & (NN - 1);
    const int* idxp = ((r >= NN) ? idx2 : idx1) + (size_t)i * (2 * SS);

    if (tid < THR) top_sh[tid] = topidx[(size_t)r * THR + tid];
    if (tid >= 192 && tid - 192 + THR < THR) {}
    for (int e = tid; e < 2 * SS; e += 256) idx_sh[e] = idxp[e];
    __syncthreads();

    int g = l >> 4, sub = l & 15, d0 = sub * 8;
    // hoist q (normalized row r) and bias for this lane's fixed dims
    float4 qa = *(const float4*)(pool_n + (size_t)r * DD + d0);
    float4 qb = *(const float4*)(pool_n + (size_t)r * DD + d0 + 4);
    float4 ba = *(const float4*)(proj_b + d0);
    float4 bb = *(const float4*)(proj_b + d0 + 4);

    float wsum = 0.f;
    for (int it = w; it < 38; it += 4) {
        int t = it * 4 + g;                       // 0..151
        int tc = (t < SS) ? t : 0;
        int c1 = top_sh[idx_sh[tc]];
        int c2 = top_sh[idx_sh[tc + SS]];
        const float* p1 = P + (size_t)c1 * DD + d0;
        const float* p2 = P + (size_t)c2 * DD + d0;
        float4 a0 = *(const float4*)p1;
        float4 a1 = *(const float4*)(p1 + 4);
        float4 b0 = *(const float4*)p2;
        float4 b1 = *(const float4*)(p2 + 4);
        float h0 = fmaf(0.2f, a0.x, fmaf(0.8f, b0.x, ba.x));
        float h1 = fmaf(0.2f, a0.y, fmaf(0.8f, b0.y, ba.y));
        float h2 = fmaf(0.2f, a0.z, fmaf(0.8f, b0.z, ba.z));
        float h3 = fmaf(0.2f, a0.w, fmaf(0.8f, b0.w, ba.w));
        float h4 = fmaf(0.2f, a1.x, fmaf(0.8f, b1.x, bb.x));
        float h5 = fmaf(0.2f, a1.y, fmaf(0.8f, b1.y, bb.y));
        float h6 = fmaf(0.2f, a1.z, fmaf(0.8f, b1.z, bb.z));
        float h7 = fmaf(0.2f, a1.w, fmaf(0.8f, b1.w, bb.w));
        float n2 = h0*h0 + h1*h1 + h2*h2 + h3*h3 + h4*h4 + h5*h5 + h6*h6 + h7*h7;
        float dt = h0*qa.x + h1*qa.y + h2*qa.z + h3*qa.w
                 + h4*qb.x + h5*qb.y + h6*qb.z + h7*qb.w;
        #pragma unroll
        for (int mask = 1; mask < 16; mask <<= 1) {
            n2 += __shfl_xor(n2, mask);
            dt += __shfl_xor(dt, mask);
        }
        float e = expf(2.0f * dt / fmaxf(sqrtf(n2), 1e-12f));
        wsum += (t < SS && sub == 0) ? e : 0.f;
    }
    #pragma unroll
    for (int mask = 1; mask < 64; mask <<= 1) wsum += __shfl_xor(wsum, mask);
    if (l == 0) red2[w] = wsum;
    __syncthreads();
    if (tid == 0) {
        float negm = red2[0] + red2[1] + red2[2] + red2[3];
        float den = negsum[r] + negm - refl[r];
        float loss = logf(den) - 2.0f * posd[r];
        atomicAdd(out, loss * (1.0f / 4096.0f));
    }
}

extern "C" void kernel_launch(void* const* d_in, const int* in_sizes, int n_in,
                              void* d_out, int out_size, void* d_ws, size_t ws_size,
                              hipStream_t stream) {
    const float* z1  = (const float*)d_in[0];
    const float* z2  = (const float*)d_in[1];
    const float* pw  = (const float*)d_in[2];
    const float* pb  = (const float*)d_in[3];
    const int* idx1  = (const int*)d_in[4];
    const int* idx2  = (const int*)d_in[5];
    float* out = (float*)d_out;

    float* wsf = (float*)d_ws;
    float* pool_n  = wsf + OFF_POOLN;
    float* pool_nT = wsf + OFF_POOLT;
    float* wtT     = wsf + OFF_WTT;
    float* Pm      = wsf + OFF_PROJ;
    float* negs    = wsf + OFF_NEG;
    float* rfl     = wsf + OFF_REFL;
    float* psd     = wsf + OFF_POSD;
    int*   topi    = (int*)(wsf + OFF_TOPI);

    hipMemsetAsync(d_out, 0, sizeof(float), stream);

    prep_norm<<<PP, 64, 0, stream>>>(z1, z2, pool_n, pool_nT);
    prep_wt<<<64, 256, 0, stream>>>(pw, wtT);
    prep_proj<<<PP / 8, 256, 0, stream>>>(z1, z2, wtT, Pm);
    simtopk<<<PP / ROWS, 256, 0, stream>>>(pool_n, pool_nT, negs, rfl, psd, topi);
    mixloss<<<PP, 256, 0, stream>>>(Pm, pool_n, pb, negs, rfl, psd, topi,
                                    idx1, idx2, out);
}

// Round 4
// 329.098 us; speedup vs baseline: 2.9729x; 1.1286x over previous
//
#include <hip/hip_runtime.h>
#include <math.h>

#define NN 2048
#define PP 4096
#define DD 128
#define SS 150
#define THR 204
#define ROWS 8
#define TPB 512
#define CAP 512

// ws layout (float offsets)
#define OFF_POOLN 0
#define OFF_POOLT 524288
#define OFF_WTT   1048576   // 16384 floats (W^T, [k][d])
#define OFF_PROJ  1064960   // 4096*128 floats = z_pool @ W^T
#define OFF_NEG   1589248
#define OFF_REFL  1593344
#define OFF_POSD  1597440
#define OFF_TOPI  1601536   // 4096*204 ints

// ---------------- prep: normalize pool rows, write normal + transposed ----------------
__global__ void prep_norm(const float* __restrict__ z1, const float* __restrict__ z2,
                          float* __restrict__ pool_n, float* __restrict__ pool_nT) {
    int b = blockIdx.x;          // pool row 0..4095
    int l = threadIdx.x;         // 0..63
    const float* src = (b < NN) ? z1 + (size_t)b * DD : z2 + (size_t)(b - NN) * DD;
    float2 v = *(const float2*)(src + 2 * l);
    float ss = v.x * v.x + v.y * v.y;
    #pragma unroll
    for (int mask = 1; mask < 64; mask <<= 1) ss += __shfl_xor(ss, mask);
    float inv = 1.0f / fmaxf(sqrtf(ss), 1e-12f);
    float2 nv; nv.x = v.x * inv; nv.y = v.y * inv;
    *(float2*)(pool_n + (size_t)b * DD + 2 * l) = nv;
    pool_nT[(size_t)(2 * l) * PP + b]     = nv.x;
    pool_nT[(size_t)(2 * l + 1) * PP + b] = nv.y;
}

// ---------------- prep: transpose proj_w (fp32), layout [k][d] ----------------
__global__ void prep_wt(const float* __restrict__ pw, float* __restrict__ wtT) {
    int e = blockIdx.x * 256 + threadIdx.x;   // 0..16383
    int k = e >> 7, d = e & 127;
    wtT[e] = pw[d * DD + k];
}

// ---------------- prep: P = z_pool @ W^T (no bias) ----------------
__global__ __launch_bounds__(256, 4) void prep_proj(
    const float* __restrict__ z1, const float* __restrict__ z2,
    const float* __restrict__ wtT, float* __restrict__ P) {
    __shared__ float z_sh[8][DD];
    int tid = threadIdx.x;
    int r0 = blockIdx.x * 8;
    for (int e = tid; e < 8 * DD; e += 256) {
        int rr = r0 + (e >> 7);
        z_sh[e >> 7][e & 127] = (rr < NN) ? z1[(size_t)rr * DD + (e & 127)]
                                          : z2[(size_t)(rr - NN) * DD + (e & 127)];
    }
    __syncthreads();
    int d = tid & 127, h = tid >> 7;
    float a0 = 0.f, a1 = 0.f, a2 = 0.f, a3 = 0.f;
    for (int k = 0; k < DD; k++) {
        float wv = wtT[k * DD + d];
        a0 += z_sh[4 * h + 0][k] * wv;
        a1 += z_sh[4 * h + 1][k] * wv;
        a2 += z_sh[4 * h + 2][k] * wv;
        a3 += z_sh[4 * h + 3][k] * wv;
    }
    P[(size_t)(r0 + 4 * h + 0) * DD + d] = a0;
    P[(size_t)(r0 + 4 * h + 1) * DD + d] = a1;
    P[(size_t)(r0 + 4 * h + 2) * DD + d] = a2;
    P[(size_t)(r0 + 4 * h + 3) * DD + d] = a3;
}

// order-preserving float->uint key (larger float => larger key)
__device__ __forceinline__ unsigned fkey(float v) {
    unsigned u = __float_as_uint(v);
    return u ^ (unsigned)(((int)u >> 31) | 0x80000000);
}

// ---------------- Gram rows + expsum + top-204 via radix-select + rank ----------------
// 512 threads, 8 rows/block, 8 cols/thread -> acc[8][8] = 64 VGPR, no spill.
__global__ __launch_bounds__(TPB, 4) void simtopk(
    const float* __restrict__ pool_n, const float* __restrict__ pool_nT,
    float* __restrict__ negsum, float* __restrict__ refl, float* __restrict__ posd,
    int* __restrict__ topidx) {
    __shared__ float q_sh[ROWS][DD];          // 4 KB
    __shared__ int hist[ROWS][256];           // 8 KB
    __shared__ uint2 cand[ROWS][CAP];         // 32 KB  {key, col}
    __shared__ int rowB[ROWS], rowCum[ROWS], rowP[ROWS], cnt[ROWS];
    __shared__ float partial[ROWS][8];

    int tid = threadIdx.x, w = tid >> 6, l = tid & 63;
    int r0 = blockIdx.x * ROWS;

    for (int e = tid; e < ROWS * DD; e += TPB)
        q_sh[e >> 7][e & 127] = pool_n[(size_t)r0 * DD + e];
    __syncthreads();

    float acc[ROWS][8];
    #pragma unroll
    for (int r = 0; r < ROWS; r++)
        #pragma unroll
        for (int e = 0; e < 8; e++) acc[r][e] = 0.f;

    // gram: thread tid owns cols {jj*2048 + tid*4 + c : jj in {0,1}, c in 0..3}
    const float4* pt4 = (const float4*)pool_nT;
    for (int k = 0; k < DD; k++) {
        float4 p0 = pt4[k * 1024 + tid];
        float4 p1 = pt4[k * 1024 + 512 + tid];
        #pragma unroll
        for (int r = 0; r < ROWS; r++) {
            float qk = q_sh[r][k];
            acc[r][0] += qk * p0.x; acc[r][1] += qk * p0.y; acc[r][2] += qk * p0.z; acc[r][3] += qk * p0.w;
            acc[r][4] += qk * p1.x; acc[r][5] += qk * p1.y; acc[r][6] += qk * p1.z; acc[r][7] += qk * p1.w;
        }
    }

    // expsum (full row = k=2N top_k sum) + refl/posd (constant acc indices)
    #pragma unroll
    for (int r = 0; r < ROWS; r++) {
        int rg = r0 + r;
        float es = 0.f;
        #pragma unroll
        for (int e = 0; e < 8; e++) {
            es += expf(2.0f * acc[r][e]);
            int col = (e >> 2) * 2048 + (tid << 2) + (e & 3);
            if (col == rg) refl[rg] = acc[r][e];
            if (col == (rg ^ NN)) posd[rg] = acc[r][e];
        }
        #pragma unroll
        for (int mask = 1; mask < 64; mask <<= 1) es += __shfl_xor(es, mask);
        if (l == 0) partial[r][w] = es;
    }

    // ---- radix pass 1: 256-bin hist of key[31:24] ----
    for (int e = tid; e < ROWS * 256; e += TPB) ((int*)hist)[e] = 0;
    if (tid < ROWS) cnt[tid] = 0;
    __syncthreads();
    if (tid < ROWS) {
        float s = 0.f;
        #pragma unroll
        for (int ww = 0; ww < 8; ww++) s += partial[tid][ww];
        negsum[r0 + tid] = s;
    }
    #pragma unroll
    for (int r = 0; r < ROWS; r++)
        #pragma unroll
        for (int e = 0; e < 8; e++)
            atomicAdd(&hist[r][fkey(acc[r][e]) >> 24], 1);
    __syncthreads();

    // scan1: wave w handles row w
    {
        int rr = w;
        int4 h4 = ((const int4*)hist[rr])[l];     // bins 4l..4l+3
        int s = h4.x + h4.y + h4.z + h4.w;
        int suf = s;
        #pragma unroll
        for (int off = 1; off < 64; off <<= 1) {
            int x = __shfl_down(suf, off);
            if (l + off < 64) suf += x;
        }
        int A = suf - s;                           // count above this lane's bins
        int ca3 = A, ca2 = A + h4.w, ca1 = ca2 + h4.z, ca0 = ca1 + h4.y;
        if (ca3 < THR && THR <= ca3 + h4.w) { rowB[rr] = 4 * l + 3; rowCum[rr] = ca3; }
        if (ca2 < THR && THR <= ca2 + h4.z) { rowB[rr] = 4 * l + 2; rowCum[rr] = ca2; }
        if (ca1 < THR && THR <= ca1 + h4.y) { rowB[rr] = 4 * l + 1; rowCum[rr] = ca1; }
        if (ca0 < THR && THR <= ca0 + h4.x) { rowB[rr] = 4 * l + 0; rowCum[rr] = ca0; }
    }
    __syncthreads();

    // ---- radix pass 2: hist of key[23:16] within selected top-8 bin ----
    for (int e = tid; e < ROWS * 256; e += TPB) ((int*)hist)[e] = 0;
    __syncthreads();
    #pragma unroll
    for (int r = 0; r < ROWS; r++) {
        int B = rowB[r];
        #pragma unroll
        for (int e = 0; e < 8; e++) {
            unsigned key = fkey(acc[r][e]);
            if ((int)(key >> 24) == B) atomicAdd(&hist[r][(key >> 16) & 255], 1);
        }
    }
    __syncthreads();

    {
        int rr = w;
        int base = rowCum[rr];
        int4 h4 = ((const int4*)hist[rr])[l];
        int s = h4.x + h4.y + h4.z + h4.w;
        int suf = s;
        #pragma unroll
        for (int off = 1; off < 64; off <<= 1) {
            int x = __shfl_down(suf, off);
            if (l + off < 64) suf += x;
        }
        int A = base + suf - s;
        int ca3 = A, ca2 = A + h4.w, ca1 = ca2 + h4.z, ca0 = ca1 + h4.y;
        if (ca3 < THR && THR <= ca3 + h4.w) rowP[rr] = (rowB[rr] << 8) | (4 * l + 3);
        if (ca2 < THR && THR <= ca2 + h4.z) rowP[rr] = (rowB[rr] << 8) | (4 * l + 2);
        if (ca1 < THR && THR <= ca1 + h4.y) rowP[rr] = (rowB[rr] << 8) | (4 * l + 1);
        if (ca0 < THR && THR <= ca0 + h4.x) rowP[rr] = (rowB[rr] << 8) | (4 * l + 0);
    }
    __syncthreads();

    // ---- collect candidates with key>>16 >= P16 ----
    #pragma unroll
    for (int r = 0; r < ROWS; r++) {
        unsigned P16 = (unsigned)rowP[r];
        #pragma unroll
        for (int e = 0; e < 8; e++) {
            unsigned key = fkey(acc[r][e]);
            if ((key >> 16) >= P16) {
                int p = atomicAdd(&cnt[r], 1);
                if (p < CAP) {
                    int col = (e >> 2) * 2048 + (tid << 2) + (e & 3);
                    cand[r][p] = make_uint2(key, (unsigned)col);
                }
            }
        }
    }
    __syncthreads();

    // ---- rank candidates (key desc, col asc); wave w ranks row w ----
    {
        int rr = w;
        int C = min(cnt[rr], CAP);
        int rg = r0 + rr;
        unsigned km[8]; int im[8], rk[8];
        #pragma unroll
        for (int o = 0; o < 8; o++) {
            int b = l + o * 64;
            bool v = (b < C);
            uint2 cd = v ? cand[rr][b] : make_uint2(0u, 0u);
            km[o] = cd.x; im[o] = (int)cd.y; rk[o] = v ? 0 : (THR + CAP);
        }
        for (int c = 0; c < C; c++) {
            uint2 cd = cand[rr][c];
            unsigned kc = cd.x; int ic = (int)cd.y;
            #pragma unroll
            for (int o = 0; o < 8; o++)
                if (o * 64 < C)
                    rk[o] += (kc > km[o] || (kc == km[o] && ic < im[o])) ? 1 : 0;
        }
        #pragma unroll
        for (int o = 0; o < 8; o++)
            if (rk[o] < THR) topidx[(size_t)rg * THR + rk[o]] = im[o];
    }
}

// ---------------- mix (via linearity) + normalize + dot + loss ----------------
__global__ __launch_bounds__(256, 4) void mixloss(
    const float* __restrict__ P, const float* __restrict__ pool_n,
    const float* __restrict__ proj_b,
    const float* __restrict__ negsum, const float* __restrict__ refl,
    const float* __restrict__ posd, const int* __restrict__ topidx,
    const int* __restrict__ idx1, const int* __restrict__ idx2,
    float* __restrict__ out) {
    __shared__ int top_sh[THR];
    __shared__ int idx_sh[2 * SS];
    __shared__ float red2[4];

    int tid = threadIdx.x, w = tid >> 6, l = tid & 63;
    int r = blockIdx.x;                   // 0..4095
    int i = r & (NN - 1);
    const int* idxp = ((r >= NN) ? idx2 : idx1) + (size_t)i * (2 * SS);

    if (tid < THR) top_sh[tid] = topidx[(size_t)r * THR + tid];
    for (int e = tid; e < 2 * SS; e += 256) idx_sh[e] = idxp[e];
    __syncthreads();

    int g = l >> 4, sub = l & 15, d0 = sub * 8;
    // hoist q (normalized row r) and bias for this lane's fixed dims
    float4 qa = *(const float4*)(pool_n + (size_t)r * DD + d0);
    float4 qb = *(const float4*)(pool_n + (size_t)r * DD + d0 + 4);
    float4 ba = *(const float4*)(proj_b + d0);
    float4 bb = *(const float4*)(proj_b + d0 + 4);

    float wsum = 0.f;
    for (int it = w; it < 38; it += 4) {
        int t = it * 4 + g;                       // 0..151
        int tc = (t < SS) ? t : 0;
        int c1 = top_sh[idx_sh[tc]];
        int c2 = top_sh[idx_sh[tc + SS]];
        const float* p1 = P + (size_t)c1 * DD + d0;
        const float* p2 = P + (size_t)c2 * DD + d0;
        float4 a0 = *(const float4*)p1;
        float4 a1 = *(const float4*)(p1 + 4);
        float4 b0 = *(const float4*)p2;
        float4 b1 = *(const float4*)(p2 + 4);
        float h0 = fmaf(0.2f, a0.x, fmaf(0.8f, b0.x, ba.x));
        float h1 = fmaf(0.2f, a0.y, fmaf(0.8f, b0.y, ba.y));
        float h2 = fmaf(0.2f, a0.z, fmaf(0.8f, b0.z, ba.z));
        float h3 = fmaf(0.2f, a0.w, fmaf(0.8f, b0.w, ba.w));
        float h4 = fmaf(0.2f, a1.x, fmaf(0.8f, b1.x, bb.x));
        float h5 = fmaf(0.2f, a1.y, fmaf(0.8f, b1.y, bb.y));
        float h6 = fmaf(0.2f, a1.z, fmaf(0.8f, b1.z, bb.z));
        float h7 = fmaf(0.2f, a1.w, fmaf(0.8f, b1.w, bb.w));
        float n2 = h0*h0 + h1*h1 + h2*h2 + h3*h3 + h4*h4 + h5*h5 + h6*h6 + h7*h7;
        float dt = h0*qa.x + h1*qa.y + h2*qa.z + h3*qa.w
                 + h4*qb.x + h5*qb.y + h6*qb.z + h7*qb.w;
        #pragma unroll
        for (int mask = 1; mask < 16; mask <<= 1) {
            n2 += __shfl_xor(n2, mask);
            dt += __shfl_xor(dt, mask);
        }
        float e = expf(2.0f * dt / fmaxf(sqrtf(n2), 1e-12f));
        wsum += (t < SS && sub == 0) ? e : 0.f;
    }
    #pragma unroll
    for (int mask = 1; mask < 64; mask <<= 1) wsum += __shfl_xor(wsum, mask);
    if (l == 0) red2[w] = wsum;
    __syncthreads();
    if (tid == 0) {
        float negm = red2[0] + red2[1] + red2[2] + red2[3];
        float den = negsum[r] + negm - refl[r];
        float loss = logf(den) - 2.0f * posd[r];
        atomicAdd(out, loss * (1.0f / 4096.0f));
    }
}

extern "C" void kernel_launch(void* const* d_in, const int* in_sizes, int n_in,
                              void* d_out, int out_size, void* d_ws, size_t ws_size,
                              hipStream_t stream) {
    const float* z1  = (const float*)d_in[0];
    const float* z2  = (const float*)d_in[1];
    const float* pw  = (const float*)d_in[2];
    const float* pb  = (const float*)d_in[3];
    const int* idx1  = (const int*)d_in[4];
    const int* idx2  = (const int*)d_in[5];
    float* out = (float*)d_out;

    float* wsf = (float*)d_ws;
    float* pool_n  = wsf + OFF_POOLN;
    float* pool_nT = wsf + OFF_POOLT;
    float* wtT     = wsf + OFF_WTT;
    float* Pm      = wsf + OFF_PROJ;
    float* negs    = wsf + OFF_NEG;
    float* rfl     = wsf + OFF_REFL;
    float* psd     = wsf + OFF_POSD;
    int*   topi    = (int*)(wsf + OFF_TOPI);

    hipMemsetAsync(d_out, 0, sizeof(float), stream);

    prep_norm<<<PP, 64, 0, stream>>>(z1, z2, pool_n, pool_nT);
    prep_wt<<<64, 256, 0, stream>>>(pw, wtT);
    prep_proj<<<PP / 8, 256, 0, stream>>>(z1, z2, wtT, Pm);
    simtopk<<<PP / ROWS, TPB, 0, stream>>>(pool_n, pool_nT, negs, rfl, psd, topi);
    mixloss<<<PP, 256, 0, stream>>>(Pm, pool_n, pb, negs, rfl, psd, topi,
                                    idx1, idx2, out);
}

// Round 5
// 162.819 us; speedup vs baseline: 6.0089x; 2.0212x over previous
//
#include <hip/hip_runtime.h>
#include <math.h>

#define NN 2048
#define PP 4096
#define DD 128
#define SS 150
#define THR 204
#define ROWS 8
#define TPB 512
#define CAP 512

typedef float f32x4 __attribute__((ext_vector_type(4)));
typedef short s16x8 __attribute__((ext_vector_type(8)));

// ws layout (float offsets)
#define OFF_POOLN 0
#define OFF_POOLT 524288
#define OFF_WTT   1048576   // 16384 floats (W^T, [k][d])
#define OFF_PROJ  1064960   // 4096*128 floats = z_pool @ W^T
#define OFF_NEG   1589248
#define OFF_REFL  1593344
#define OFF_POSD  1597440
#define OFF_TOPI  1601536   // 4096*204 ints
#define OFF_POOLB 2437120   // 4096*128 bf16 (ushort) = 262144 floats
#define OFF_SIMS  2699264   // 4096*4096 fp32 = 64 MB
#define WS_FAST_FLOATS (OFF_SIMS + (size_t)PP * PP)

// ---------------- prep: normalize pool rows; fp32 row-major + fp32 transposed + bf16 ----------------
__global__ void prep_norm(const float* __restrict__ z1, const float* __restrict__ z2,
                          float* __restrict__ pool_n, float* __restrict__ pool_nT,
                          unsigned short* __restrict__ poolb) {
    int b = blockIdx.x;          // pool row 0..4095
    int l = threadIdx.x;         // 0..63
    const float* src = (b < NN) ? z1 + (size_t)b * DD : z2 + (size_t)(b - NN) * DD;
    float2 v = *(const float2*)(src + 2 * l);
    float ss = v.x * v.x + v.y * v.y;
    #pragma unroll
    for (int mask = 1; mask < 64; mask <<= 1) ss += __shfl_xor(ss, mask);
    float inv = 1.0f / fmaxf(sqrtf(ss), 1e-12f);
    float2 nv; nv.x = v.x * inv; nv.y = v.y * inv;
    *(float2*)(pool_n + (size_t)b * DD + 2 * l) = nv;
    pool_nT[(size_t)(2 * l) * PP + b]     = nv.x;
    pool_nT[(size_t)(2 * l + 1) * PP + b] = nv.y;
    // bf16 RNE pack
    unsigned ux = __float_as_uint(nv.x); ux = (ux + 0x7FFFu + ((ux >> 16) & 1u)) >> 16;
    unsigned uy = __float_as_uint(nv.y); uy = (uy + 0x7FFFu + ((uy >> 16) & 1u)) >> 16;
    ((unsigned*)poolb)[(size_t)b * 64 + l] = ux | (uy << 16);
}

// ---------------- prep: transpose proj_w (fp32), layout [k][d] ----------------
__global__ void prep_wt(const float* __restrict__ pw, float* __restrict__ wtT) {
    int e = blockIdx.x * 256 + threadIdx.x;   // 0..16383
    int k = e >> 7, d = e & 127;
    wtT[e] = pw[d * DD + k];
}

// ---------------- prep: P = z_pool @ W^T (no bias) ----------------
__global__ __launch_bounds__(256, 4) void prep_proj(
    const float* __restrict__ z1, const float* __restrict__ z2,
    const float* __restrict__ wtT, float* __restrict__ P) {
    __shared__ float z_sh[8][DD];
    int tid = threadIdx.x;
    int r0 = blockIdx.x * 8;
    for (int e = tid; e < 8 * DD; e += 256) {
        int rr = r0 + (e >> 7);
        z_sh[e >> 7][e & 127] = (rr < NN) ? z1[(size_t)rr * DD + (e & 127)]
                                          : z2[(size_t)(rr - NN) * DD + (e & 127)];
    }
    __syncthreads();
    int d = tid & 127, h = tid >> 7;
    float a0 = 0.f, a1 = 0.f, a2 = 0.f, a3 = 0.f;
    for (int k = 0; k < DD; k++) {
        float wv = wtT[k * DD + d];
        a0 += z_sh[4 * h + 0][k] * wv;
        a1 += z_sh[4 * h + 1][k] * wv;
        a2 += z_sh[4 * h + 2][k] * wv;
        a3 += z_sh[4 * h + 3][k] * wv;
    }
    P[(size_t)(r0 + 4 * h + 0) * DD + d] = a0;
    P[(size_t)(r0 + 4 * h + 1) * DD + d] = a1;
    P[(size_t)(r0 + 4 * h + 2) * DD + d] = a2;
    P[(size_t)(r0 + 4 * h + 3) * DD + d] = a3;
}

// order-preserving float->uint key (larger float => larger key)
__device__ __forceinline__ unsigned fkey(float v) {
    unsigned u = __float_as_uint(v);
    return u ^ (unsigned)(((int)u >> 31) | 0x80000000);
}

// ---------------- FAST PATH A: sims = poolb @ poolb^T via MFMA, fp32 out ----------------
// 256 thr / 4 waves; block tile 128x128; wave tile 64x64 = 4x4 frags of 16x16; K=128 in 4 steps.
#define LDA 136   // shorts per LDS row (128 + 8 pad -> 272 B stride, 2-way bank alias only)
__global__ __launch_bounds__(256) void gram_mfma(
    const unsigned short* __restrict__ poolb, float* __restrict__ sims) {
    __shared__ short tiles[2 * 128 * LDA];   // 69.6 KB
    short* As = tiles;
    short* Bs = tiles + 128 * LDA;

    int tid = threadIdx.x;
    int bi = blockIdx.x >> 5, bj = blockIdx.x & 31;
    int r0 = bi * 128, c0 = bj * 128;

    // stage A rows r0..r0+127 and B rows c0..c0+127 (each 32 KB contiguous in global)
    const unsigned short* gA = poolb + (size_t)r0 * DD;
    const unsigned short* gB = poolb + (size_t)c0 * DD;
    #pragma unroll
    for (int it = 0; it < 8; it++) {
        int g = it * 256 + tid;              // 16-byte chunk id, 2048 chunks per tile
        int row = g >> 4, ch = (g & 15) * 8; // short offsets
        *(s16x8*)&As[row * LDA + ch] = *(const s16x8*)(gA + row * DD + ch);
        *(s16x8*)&Bs[row * LDA + ch] = *(const s16x8*)(gB + row * DD + ch);
    }
    __syncthreads();

    int l = tid & 63, w = tid >> 6;
    int wr = (w >> 1) * 64, wc = (w & 1) * 64;
    int lr = l & 15, lk = (l >> 4) * 8;

    f32x4 zero = {0.f, 0.f, 0.f, 0.f};
    f32x4 acc[4][4];
    #pragma unroll
    for (int m = 0; m < 4; m++)
        #pragma unroll
        for (int n = 0; n < 4; n++) acc[m][n] = zero;

    #pragma unroll
    for (int kk = 0; kk < 4; kk++) {
        int ko = kk * 32 + lk;
        s16x8 av[4], bv[4];
        #pragma unroll
        for (int m = 0; m < 4; m++)
            av[m] = *(const s16x8*)&As[(wr + m * 16 + lr) * LDA + ko];
        #pragma unroll
        for (int n = 0; n < 4; n++)
            bv[n] = *(const s16x8*)&Bs[(wc + n * 16 + lr) * LDA + ko];
        #pragma unroll
        for (int m = 0; m < 4; m++)
            #pragma unroll
            for (int n = 0; n < 4; n++)
                acc[m][n] = __builtin_amdgcn_mfma_f32_16x16x32_bf16(av[m], bv[n], acc[m][n], 0, 0, 0);
    }

    // C write: row = (l>>4)*4 + reg, col = l&15 within each 16x16 frag
    int fq = (l >> 4) * 4, fr = l & 15;
    #pragma unroll
    for (int m = 0; m < 4; m++)
        #pragma unroll
        for (int n = 0; n < 4; n++) {
            size_t base = (size_t)(r0 + wr + m * 16 + fq) * PP + (c0 + wc + n * 16 + fr);
            #pragma unroll
            for (int reg = 0; reg < 4; reg++)
                sims[base + (size_t)reg * PP] = acc[m][n][reg];
        }
}

// ---------------- FAST PATH B: per-row expsum + refl/posd + top-204 select ----------------
__global__ __launch_bounds__(256) void rowselect(
    const float* __restrict__ sims,
    float* __restrict__ negsum, float* __restrict__ refl, float* __restrict__ posd,
    int* __restrict__ topidx) {
    __shared__ int hist[256];
    __shared__ uint2 cand[CAP];
    __shared__ float part[4];
    __shared__ int scal[4];   // 0:B  1:cum  2:P16  3:cnt

    int tid = threadIdx.x, w = tid >> 6, l = tid & 63;
    int r = blockIdx.x;
    const float4* rp = (const float4*)(sims + (size_t)r * PP);

    float4 va[4];
    float es = 0.f;
    #pragma unroll
    for (int j = 0; j < 4; j++) {
        va[j] = rp[tid + j * 256];
        es += expf(2.0f * va[j].x) + expf(2.0f * va[j].y)
            + expf(2.0f * va[j].z) + expf(2.0f * va[j].w);
    }
    #pragma unroll
    for (int mask = 1; mask < 64; mask <<= 1) es += __shfl_xor(es, mask);
    if (l == 0) part[w] = es;

    hist[tid] = 0;
    if (tid == 0) scal[3] = 0;
    // refl / posd: the thread owning that column writes it
    #pragma unroll
    for (int j = 0; j < 4; j++) {
        int col0 = (tid + j * 256) * 4;
        #pragma unroll
        for (int c = 0; c < 4; c++) {
            float v = (c == 0) ? va[j].x : (c == 1) ? va[j].y : (c == 2) ? va[j].z : va[j].w;
            if (col0 + c == r) refl[r] = v;
            if (col0 + c == (r ^ NN)) posd[r] = v;
        }
    }
    __syncthreads();
    if (tid == 0) negsum[r] = part[0] + part[1] + part[2] + part[3];

    // hist1 on key[31:24]
    #pragma unroll
    for (int j = 0; j < 4; j++) {
        atomicAdd(&hist[fkey(va[j].x) >> 24], 1);
        atomicAdd(&hist[fkey(va[j].y) >> 24], 1);
        atomicAdd(&hist[fkey(va[j].z) >> 24], 1);
        atomicAdd(&hist[fkey(va[j].w) >> 24], 1);
    }
    __syncthreads();
    if (w == 0) {
        int4 h4 = ((const int4*)hist)[l];
        int s = h4.x + h4.y + h4.z + h4.w;
        int suf = s;
        #pragma unroll
        for (int off = 1; off < 64; off <<= 1) {
            int x = __shfl_down(suf, off);
            if (l + off < 64) suf += x;
        }
        int A = suf - s;
        int ca3 = A, ca2 = A + h4.w, ca1 = ca2 + h4.z, ca0 = ca1 + h4.y;
        if (ca3 < THR && THR <= ca3 + h4.w) { scal[0] = 4 * l + 3; scal[1] = ca3; }
        if (ca2 < THR && THR <= ca2 + h4.z) { scal[0] = 4 * l + 2; scal[1] = ca2; }
        if (ca1 < THR && THR <= ca1 + h4.y) { scal[0] = 4 * l + 1; scal[1] = ca1; }
        if (ca0 < THR && THR <= ca0 + h4.x) { scal[0] = 4 * l + 0; scal[1] = ca0; }
    }
    __syncthreads();
    int B = scal[0], base = scal[1];
    hist[tid] = 0;
    __syncthreads();

    // hist2 on key[23:16] within bin B
    #pragma unroll
    for (int j = 0; j < 4; j++) {
        #pragma unroll
        for (int c = 0; c < 4; c++) {
            float v = (c == 0) ? va[j].x : (c == 1) ? va[j].y : (c == 2) ? va[j].z : va[j].w;
            unsigned key = fkey(v);
            if ((int)(key >> 24) == B) atomicAdd(&hist[(key >> 16) & 255], 1);
        }
    }
    __syncthreads();
    if (w == 0) {
        int4 h4 = ((const int4*)hist)[l];
        int s = h4.x + h4.y + h4.z + h4.w;
        int suf = s;
        #pragma unroll
        for (int off = 1; off < 64; off <<= 1) {
            int x = __shfl_down(suf, off);
            if (l + off < 64) suf += x;
        }
        int A = base + suf - s;
        int ca3 = A, ca2 = A + h4.w, ca1 = ca2 + h4.z, ca0 = ca1 + h4.y;
        if (ca3 < THR && THR <= ca3 + h4.w) scal[2] = (B << 8) | (4 * l + 3);
        if (ca2 < THR && THR <= ca2 + h4.z) scal[2] = (B << 8) | (4 * l + 2);
        if (ca1 < THR && THR <= ca1 + h4.y) scal[2] = (B << 8) | (4 * l + 1);
        if (ca0 < THR && THR <= ca0 + h4.x) scal[2] = (B << 8) | (4 * l + 0);
    }
    __syncthreads();
    unsigned P16 = (unsigned)scal[2];

    // collect candidates
    #pragma unroll
    for (int j = 0; j < 4; j++) {
        int col0 = (tid + j * 256) * 4;
        #pragma unroll
        for (int c = 0; c < 4; c++) {
            float v = (c == 0) ? va[j].x : (c == 1) ? va[j].y : (c == 2) ? va[j].z : va[j].w;
            unsigned key = fkey(v);
            if ((key >> 16) >= P16) {
                int p = atomicAdd(&scal[3], 1);
                if (p < CAP) cand[p] = make_uint2(key, (unsigned)(col0 + c));
            }
        }
    }
    __syncthreads();

    // rank (key desc, col asc)
    int C = min(scal[3], CAP);
    #pragma unroll
    for (int o = 0; o < 2; o++) {
        int t = tid + o * 256;
        if (t < C) {
            uint2 me = cand[t];
            int rk = 0;
            for (int c = 0; c < C; c++) {
                uint2 cd = cand[c];
                rk += (cd.x > me.x || (cd.x == me.x && (int)cd.y < (int)me.y)) ? 1 : 0;
            }
            if (rk < THR) topidx[(size_t)r * THR + rk] = (int)me.y;
        }
    }
}

// ---------------- FALLBACK: round-4 fused gram+select (used if ws too small) ----------------
__global__ __launch_bounds__(TPB, 4) void simtopk(
    const float* __restrict__ pool_n, const float* __restrict__ pool_nT,
    float* __restrict__ negsum, float* __restrict__ refl, float* __restrict__ posd,
    int* __restrict__ topidx) {
    __shared__ float q_sh[ROWS][DD];
    __shared__ int hist[ROWS][256];
    __shared__ uint2 cand[ROWS][CAP];
    __shared__ int rowB[ROWS], rowCum[ROWS], rowP[ROWS], cnt[ROWS];
    __shared__ float partial[ROWS][8];

    int tid = threadIdx.x, w = tid >> 6, l = tid & 63;
    int r0 = blockIdx.x * ROWS;

    for (int e = tid; e < ROWS * DD; e += TPB)
        q_sh[e >> 7][e & 127] = pool_n[(size_t)r0 * DD + e];
    __syncthreads();

    float acc[ROWS][8];
    #pragma unroll
    for (int r = 0; r < ROWS; r++)
        #pragma unroll
        for (int e = 0; e < 8; e++) acc[r][e] = 0.f;

    const float4* pt4 = (const float4*)pool_nT;
    for (int k = 0; k < DD; k++) {
        float4 p0 = pt4[k * 1024 + tid];
        float4 p1 = pt4[k * 1024 + 512 + tid];
        #pragma unroll
        for (int r = 0; r < ROWS; r++) {
            float qk = q_sh[r][k];
            acc[r][0] += qk * p0.x; acc[r][1] += qk * p0.y; acc[r][2] += qk * p0.z; acc[r][3] += qk * p0.w;
            acc[r][4] += qk * p1.x; acc[r][5] += qk * p1.y; acc[r][6] += qk * p1.z; acc[r][7] += qk * p1.w;
        }
    }

    #pragma unroll
    for (int r = 0; r < ROWS; r++) {
        int rg = r0 + r;
        float es = 0.f;
        #pragma unroll
        for (int e = 0; e < 8; e++) {
            es += expf(2.0f * acc[r][e]);
            int col = (e >> 2) * 2048 + (tid << 2) + (e & 3);
            if (col == rg) refl[rg] = acc[r][e];
            if (col == (rg ^ NN)) posd[rg] = acc[r][e];
        }
        #pragma unroll
        for (int mask = 1; mask < 64; mask <<= 1) es += __shfl_xor(es, mask);
        if (l == 0) partial[r][w] = es;
    }

    for (int e = tid; e < ROWS * 256; e += TPB) ((int*)hist)[e] = 0;
    if (tid < ROWS) cnt[tid] = 0;
    __syncthreads();
    if (tid < ROWS) {
        float s = 0.f;
        #pragma unroll
        for (int ww = 0; ww < 8; ww++) s += partial[tid][ww];
        negsum[r0 + tid] = s;
    }
    #pragma unroll
    for (int r = 0; r < ROWS; r++)
        #pragma unroll
        for (int e = 0; e < 8; e++)
            atomicAdd(&hist[r][fkey(acc[r][e]) >> 24], 1);
    __syncthreads();

    {
        int rr = w;
        int4 h4 = ((const int4*)hist[rr])[l];
        int s = h4.x + h4.y + h4.z + h4.w;
        int suf = s;
        #pragma unroll
        for (int off = 1; off < 64; off <<= 1) {
            int x = __shfl_down(suf, off);
            if (l + off < 64) suf += x;
        }
        int A = suf - s;
        int ca3 = A, ca2 = A + h4.w, ca1 = ca2 + h4.z, ca0 = ca1 + h4.y;
        if (ca3 < THR && THR <= ca3 + h4.w) { rowB[rr] = 4 * l + 3; rowCum[rr] = ca3; }
        if (ca2 < THR && THR <= ca2 + h4.z) { rowB[rr] = 4 * l + 2; rowCum[rr] = ca2; }
        if (ca1 < THR && THR <= ca1 + h4.y) { rowB[rr] = 4 * l + 1; rowCum[rr] = ca1; }
        if (ca0 < THR && THR <= ca0 + h4.x) { rowB[rr] = 4 * l + 0; rowCum[rr] = ca0; }
    }
    __syncthreads();

    for (int e = tid; e < ROWS * 256; e += TPB) ((int*)hist)[e] = 0;
    __syncthreads();
    #pragma unroll
    for (int r = 0; r < ROWS; r++) {
        int B = rowB[r];
        #pragma unroll
        for (int e = 0; e < 8; e++) {
            unsigned key = fkey(acc[r][e]);
            if ((int)(key >> 24) == B) atomicAdd(&hist[r][(key >> 16) & 255], 1);
        }
    }
    __syncthreads();

    {
        int rr = w;
        int base = rowCum[rr];
        int4 h4 = ((const int4*)hist[rr])[l];
        int s = h4.x + h4.y + h4.z + h4.w;
        int suf = s;
        #pragma unroll
        for (int off = 1; off < 64; off <<= 1) {
            int x = __shfl_down(suf, off);
            if (l + off < 64) suf += x;
        }
        int A = base + suf - s;
        int ca3 = A, ca2 = A + h4.w, ca1 = ca2 + h4.z, ca0 = ca1 + h4.y;
        if (ca3 < THR && THR <= ca3 + h4.w) rowP[rr] = (rowB[rr] << 8) | (4 * l + 3);
        if (ca2 < THR && THR <= ca2 + h4.z) rowP[rr] = (rowB[rr] << 8) | (4 * l + 2);
        if (ca1 < THR && THR <= ca1 + h4.y) rowP[rr] = (rowB[rr] << 8) | (4 * l + 1);
        if (ca0 < THR && THR <= ca0 + h4.x) rowP[rr] = (rowB[rr] << 8) | (4 * l + 0);
    }
    __syncthreads();

    #pragma unroll
    for (int r = 0; r < ROWS; r++) {
        unsigned P16 = (unsigned)rowP[r];
        #pragma unroll
        for (int e = 0; e < 8; e++) {
            unsigned key = fkey(acc[r][e]);
            if ((key >> 16) >= P16) {
                int p = atomicAdd(&cnt[r], 1);
                if (p < CAP) {
                    int col = (e >> 2) * 2048 + (tid << 2) + (e & 3);
                    cand[r][p] = make_uint2(key, (unsigned)col);
                }
            }
        }
    }
    __syncthreads();

    {
        int rr = w;
        int C = min(cnt[rr], CAP);
        int rg = r0 + rr;
        unsigned km[8]; int im[8], rk[8];
        #pragma unroll
        for (int o = 0; o < 8; o++) {
            int b = l + o * 64;
            bool v = (b < C);
            uint2 cd = v ? cand[rr][b] : make_uint2(0u, 0u);
            km[o] = cd.x; im[o] = (int)cd.y; rk[o] = v ? 0 : (THR + CAP);
        }
        for (int c = 0; c < C; c++) {
            uint2 cd = cand[rr][c];
            unsigned kc = cd.x; int ic = (int)cd.y;
            #pragma unroll
            for (int o = 0; o < 8; o++)
                if (o * 64 < C)
                    rk[o] += (kc > km[o] || (kc == km[o] && ic < im[o])) ? 1 : 0;
        }
        #pragma unroll
        for (int o = 0; o < 8; o++)
            if (rk[o] < THR) topidx[(size_t)rg * THR + rk[o]] = im[o];
    }
}

// ---------------- mix (via linearity) + normalize + dot + loss ----------------
__global__ __launch_bounds__(256, 4) void mixloss(
    const float* __restrict__ P, const float* __restrict__ pool_n,
    const float* __restrict__ proj_b,
    const float* __restrict__ negsum, const float* __restrict__ refl,
    const float* __restrict__ posd, const int* __restrict__ topidx,
    const int* __restrict__ idx1, const int* __restrict__ idx2,
    float* __restrict__ out) {
    __shared__ int top_sh[THR];
    __shared__ int idx_sh[2 * SS];
    __shared__ float red2[4];

    int tid = threadIdx.x, w = tid >> 6, l = tid & 63;
    int r = blockIdx.x;
    int i = r & (NN - 1);
    const int* idxp = ((r >= NN) ? idx2 : idx1) + (size_t)i * (2 * SS);

    if (tid < THR) top_sh[tid] = topidx[(size_t)r * THR + tid];
    for (int e = tid; e < 2 * SS; e += 256) idx_sh[e] = idxp[e];
    __syncthreads();

    int g = l >> 4, sub = l & 15, d0 = sub * 8;
    float4 qa = *(const float4*)(pool_n + (size_t)r * DD + d0);
    float4 qb = *(const float4*)(pool_n + (size_t)r * DD + d0 + 4);
    float4 ba = *(const float4*)(proj_b + d0);
    float4 bb = *(const float4*)(proj_b + d0 + 4);

    float wsum = 0.f;
    for (int it = w; it < 38; it += 4) {
        int t = it * 4 + g;                       // 0..151
        int tc = (t < SS) ? t : 0;
        int c1 = top_sh[idx_sh[tc]];
        int c2 = top_sh[idx_sh[tc + SS]];
        const float* p1 = P + (size_t)c1 * DD + d0;
        const float* p2 = P + (size_t)c2 * DD + d0;
        float4 a0 = *(const float4*)p1;
        float4 a1 = *(const float4*)(p1 + 4);
        float4 b0 = *(const float4*)p2;
        float4 b1 = *(const float4*)(p2 + 4);
        float h0 = fmaf(0.2f, a0.x, fmaf(0.8f, b0.x, ba.x));
        float h1 = fmaf(0.2f, a0.y, fmaf(0.8f, b0.y, ba.y));
        float h2 = fmaf(0.2f, a0.z, fmaf(0.8f, b0.z, ba.z));
        float h3 = fmaf(0.2f, a0.w, fmaf(0.8f, b0.w, ba.w));
        float h4 = fmaf(0.2f, a1.x, fmaf(0.8f, b1.x, bb.x));
        float h5 = fmaf(0.2f, a1.y, fmaf(0.8f, b1.y, bb.y));
        float h6 = fmaf(0.2f, a1.z, fmaf(0.8f, b1.z, bb.z));
        float h7 = fmaf(0.2f, a1.w, fmaf(0.8f, b1.w, bb.w));
        float n2 = h0*h0 + h1*h1 + h2*h2 + h3*h3 + h4*h4 + h5*h5 + h6*h6 + h7*h7;
        float dt = h0*qa.x + h1*qa.y + h2*qa.z + h3*qa.w
                 + h4*qb.x + h5*qb.y + h6*qb.z + h7*qb.w;
        #pragma unroll
        for (int mask = 1; mask < 16; mask <<= 1) {
            n2 += __shfl_xor(n2, mask);
            dt += __shfl_xor(dt, mask);
        }
        float e = expf(2.0f * dt / fmaxf(sqrtf(n2), 1e-12f));
        wsum += (t < SS && sub == 0) ? e : 0.f;
    }
    #pragma unroll
    for (int mask = 1; mask < 64; mask <<= 1) wsum += __shfl_xor(wsum, mask);
    if (l == 0) red2[w] = wsum;
    __syncthreads();
    if (tid == 0) {
        float negm = red2[0] + red2[1] + red2[2] + red2[3];
        float den = negsum[r] + negm - refl[r];
        float loss = logf(den) - 2.0f * posd[r];
        atomicAdd(out, loss * (1.0f / 4096.0f));
    }
}

extern "C" void kernel_launch(void* const* d_in, const int* in_sizes, int n_in,
                              void* d_out, int out_size, void* d_ws, size_t ws_size,
                              hipStream_t stream) {
    const float* z1  = (const float*)d_in[0];
    const float* z2  = (const float*)d_in[1];
    const float* pw  = (const float*)d_in[2];
    const float* pb  = (const float*)d_in[3];
    const int* idx1  = (const int*)d_in[4];
    const int* idx2  = (const int*)d_in[5];
    float* out = (float*)d_out;

    float* wsf = (float*)d_ws;
    float* pool_n  = wsf + OFF_POOLN;
    float* pool_nT = wsf + OFF_POOLT;
    float* wtT     = wsf + OFF_WTT;
    float* Pm      = wsf + OFF_PROJ;
    float* negs    = wsf + OFF_NEG;
    float* rfl     = wsf + OFF_REFL;
    float* psd     = wsf + OFF_POSD;
    int*   topi    = (int*)(wsf + OFF_TOPI);
    unsigned short* poolb = (unsigned short*)(wsf + OFF_POOLB);
    float* sims    = wsf + OFF_SIMS;

    hipMemsetAsync(d_out, 0, sizeof(float), stream);

    prep_norm<<<PP, 64, 0, stream>>>(z1, z2, pool_n, pool_nT, poolb);
    prep_wt<<<64, 256, 0, stream>>>(pw, wtT);
    prep_proj<<<PP / 8, 256, 0, stream>>>(z1, z2, wtT, Pm);

    if (ws_size >= WS_FAST_FLOATS * sizeof(float)) {
        gram_mfma<<<1024, 256, 0, stream>>>(poolb, sims);
        rowselect<<<PP, 256, 0, stream>>>(sims, negs, rfl, psd, topi);
    } else {
        simtopk<<<PP / ROWS, TPB, 0, stream>>>(pool_n, pool_nT, negs, rfl, psd, topi);
    }
    mixloss<<<PP, 256, 0, stream>>>(Pm, pool_n, pb, negs, rfl, psd, topi,
                                    idx1, idx2, out);
}